// Round 2
// baseline (694.348 us; speedup 1.0000x reference)
//
#include <hip/hip_runtime.h>

#define HIDDEN 1024
#define FFN    4096
#define NEXP   8
#define TOKENS 4096
#define ASSIGN 8192   // TOKENS * TOP_K

typedef __attribute__((ext_vector_type(8))) short s8v;   // 8 x bf16 (A/B frag)
typedef __attribute__((ext_vector_type(4))) float f4v;   // 4 x f32  (C/D frag)

__device__ __forceinline__ float bf2f(ushort u) {
    return __uint_as_float(((unsigned int)u) << 16);
}
__device__ __forceinline__ ushort f2bf(float f) {
    unsigned int x = __float_as_uint(f);
    return (ushort)((x + 0x7fffu + ((x >> 16) & 1u)) >> 16);  // RNE
}

#define GLDS16(g, l) __builtin_amdgcn_global_load_lds( \
    (const __attribute__((address_space(1))) unsigned int*)(g), \
    (__attribute__((address_space(3))) unsigned int*)(l), 16, 0, 0)

// ---------------- fp32 -> bf16 streaming conversion ----------------
__global__ void conv_kernel(const float4* __restrict__ src, ushort4* __restrict__ dst) {
    const int i = blockIdx.x * blockDim.x + threadIdx.x;
    const float4 v = src[i];
    ushort4 o;
    o.x = f2bf(v.x); o.y = f2bf(v.y); o.z = f2bf(v.z); o.w = f2bf(v.w);
    dst[i] = o;
}

// ---------------- router: fp32 logits -> softmax -> top2 -> counts ----------------
__global__ void router_kernel(const float* __restrict__ x, const float* __restrict__ Wr,
                              int* __restrict__ counts, int* __restrict__ topk_idx,
                              float* __restrict__ topk_w) {
    const int tok  = blockIdx.x;
    const int lane = threadIdx.x;   // block = 64 (one wave)
    float acc[NEXP];
#pragma unroll
    for (int e = 0; e < NEXP; ++e) acc[e] = 0.f;
#pragma unroll
    for (int i = 0; i < HIDDEN / 64; ++i) {
        const int idx = i * 64 + lane;
        const float xv = x[(size_t)tok * HIDDEN + idx];
#pragma unroll
        for (int e = 0; e < NEXP; ++e) acc[e] += xv * Wr[e * HIDDEN + idx];
    }
#pragma unroll
    for (int e = 0; e < NEXP; ++e) {
#pragma unroll
        for (int off = 32; off > 0; off >>= 1) acc[e] += __shfl_xor(acc[e], off);
    }
    if (lane == 0) {
        int i0 = 0;
        for (int e = 1; e < NEXP; ++e) if (acc[e] > acc[i0]) i0 = e;  // ties -> lowest idx
        int i1 = (i0 == 0) ? 1 : 0;
        for (int e = 0; e < NEXP; ++e) if (e != i0 && acc[e] > acc[i1]) i1 = e;
        const float e1 = expf(acc[i1] - acc[i0]);   // <= 1
        const float s  = 1.f + e1;
        topk_idx[tok * 2 + 0] = i0;
        topk_idx[tok * 2 + 1] = i1;
        topk_w[tok * 2 + 0]   = 1.f / s;
        topk_w[tok * 2 + 1]   = e1 / s;
        atomicAdd(&counts[i0], 1);
        atomicAdd(&counts[i1], 1);
    }
}

// ---------------- prefix over 8 counts ----------------
__global__ void prefix_kernel(const int* __restrict__ counts, int* __restrict__ offsets,
                              int* __restrict__ cursors) {
    if (threadIdx.x == 0) {
        int s = 0;
        for (int e = 0; e < NEXP; ++e) { offsets[e] = s; cursors[e] = s; s += counts[e]; }
        offsets[NEXP] = s;   // == ASSIGN
    }
}

// ---------------- compact assignments into per-expert slot lists ----------------
__global__ void scatter_kernel(const int* __restrict__ topk_idx, const float* __restrict__ topk_w,
                               int* __restrict__ cursors, int* __restrict__ token_list,
                               float* __restrict__ weight_list, int* __restrict__ slot_of) {
    const int a = blockIdx.x * blockDim.x + threadIdx.x;
    if (a >= ASSIGN) return;
    const int e   = topk_idx[a];
    const int pos = atomicAdd(&cursors[e], 1);
    token_list[pos]  = a >> 1;        // token id
    weight_list[pos] = topk_w[a];
    slot_of[a]       = pos;
}

// ---------------- GEMM1: h[slot, F] = gelu(x[tok] @ W1[e]^T + b1[e]) ----------------
__global__ __launch_bounds__(256)
void gemm1_kernel(const ushort* __restrict__ x, const ushort* __restrict__ W1,
                  const float* __restrict__ b1, const int* __restrict__ token_list,
                  const int* __restrict__ counts, const int* __restrict__ offsets,
                  ushort* __restrict__ h) {
    const int e      = blockIdx.z;
    const int n_e    = counts[e];
    const int tile_m = blockIdx.y;
    if (n_e <= 0 || tile_m * 128 >= n_e) return;
    const int tile_n = blockIdx.x;
    const int base   = offsets[e];

    __shared__ __align__(16) ushort As[128 * 32];
    __shared__ __align__(16) ushort Bs[128 * 32];

    const int t    = threadIdx.x;
    const int lane = t & 63;
    const int wv   = t >> 6;
    const int srow = t >> 2;          // 0..63 staging row
    const int scol = (t & 3) * 8;     // k-offset (elements)

    const int r0 = tile_m * 128 + srow;
    const int r1 = r0 + 64;
    const int tokA0 = token_list[base + (r0 < n_e ? r0 : n_e - 1)];
    const int tokA1 = token_list[base + (r1 < n_e ? r1 : n_e - 1)];
    const ushort* gA0 = x + (size_t)tokA0 * HIDDEN + scol;
    const ushort* gA1 = x + (size_t)tokA1 * HIDDEN + scol;
    const ushort* gB0 = W1 + ((size_t)e * FFN + tile_n * 128 + srow) * HIDDEN + scol;
    const ushort* gB1 = W1 + ((size_t)e * FFN + tile_n * 128 + 64 + srow) * HIDDEN + scol;

    ushort* lA0 = As + wv * 512;           // wave-uniform LDS bases (+lane*16B implicit)
    ushort* lA1 = As + 2048 + wv * 512;
    ushort* lB0 = Bs + wv * 512;
    ushort* lB1 = Bs + 2048 + wv * 512;

    f4v acc[4][4];
#pragma unroll
    for (int i = 0; i < 4; ++i)
#pragma unroll
        for (int j = 0; j < 4; ++j) { f4v z = {0.f, 0.f, 0.f, 0.f}; acc[i][j] = z; }

    const int row_off = (wv & 1) * 64;
    const int col_off = (wv >> 1) * 64;
    const int l15 = lane & 15;
    const int lq  = lane >> 4;

    for (int k0 = 0; k0 < HIDDEN; k0 += 32) {
        GLDS16(gA0 + k0, lA0);
        GLDS16(gA1 + k0, lA1);
        GLDS16(gB0 + k0, lB0);
        GLDS16(gB1 + k0, lB1);
        __syncthreads();
        s8v a[4], b[4];
#pragma unroll
        for (int i = 0; i < 4; ++i) a[i] = *(const s8v*)(As + (row_off + i * 16 + l15) * 32 + lq * 8);
#pragma unroll
        for (int j = 0; j < 4; ++j) b[j] = *(const s8v*)(Bs + (col_off + j * 16 + l15) * 32 + lq * 8);
#pragma unroll
        for (int i = 0; i < 4; ++i)
#pragma unroll
            for (int j = 0; j < 4; ++j)
                acc[i][j] = __builtin_amdgcn_mfma_f32_16x16x32_bf16(a[i], b[j], acc[i][j], 0, 0, 0);
        __syncthreads();
    }

    const int mrem = n_e - tile_m * 128;
#pragma unroll
    for (int i = 0; i < 4; ++i) {
#pragma unroll
        for (int r = 0; r < 4; ++r) {
            const int m_loc = row_off + i * 16 + lq * 4 + r;
            if (m_loc < mrem) {
                const size_t hrow = (size_t)(base + tile_m * 128 + m_loc) * FFN;
#pragma unroll
                for (int j = 0; j < 4; ++j) {
                    const int colF = tile_n * 128 + col_off + j * 16 + l15;
                    float v = acc[i][j][r] + b1[e * FFN + colF];
                    v = 0.5f * v * (1.0f + erff(v * 0.70710678118654752f));  // exact gelu
                    h[hrow + colF] = f2bf(v);
                }
            }
        }
    }
}

// ---------------- GEMM2: y[slot, D] = (h[slot] @ W2[e]^T + b2[e]) * gate ----------------
__global__ __launch_bounds__(256)
void gemm2_kernel(const ushort* __restrict__ h, const ushort* __restrict__ W2,
                  const float* __restrict__ b2, const float* __restrict__ weight_list,
                  const int* __restrict__ counts, const int* __restrict__ offsets,
                  ushort* __restrict__ y) {
    const int e      = blockIdx.z;
    const int n_e    = counts[e];
    const int tile_m = blockIdx.y;
    if (n_e <= 0 || tile_m * 128 >= n_e) return;
    const int tile_n = blockIdx.x;   // 0..7
    const int base   = offsets[e];

    __shared__ __align__(16) ushort As[128 * 32];
    __shared__ __align__(16) ushort Bs[128 * 32];

    const int t    = threadIdx.x;
    const int lane = t & 63;
    const int wv   = t >> 6;
    const int srow = t >> 2;
    const int scol = (t & 3) * 8;

    const int r0 = tile_m * 128 + srow;
    const int r1 = r0 + 64;
    const int slot0 = base + (r0 < n_e ? r0 : n_e - 1);
    const int slot1 = base + (r1 < n_e ? r1 : n_e - 1);
    const ushort* gA0 = h + (size_t)slot0 * FFN + scol;
    const ushort* gA1 = h + (size_t)slot1 * FFN + scol;
    const ushort* gB0 = W2 + ((size_t)e * HIDDEN + tile_n * 128 + srow) * FFN + scol;
    const ushort* gB1 = W2 + ((size_t)e * HIDDEN + tile_n * 128 + 64 + srow) * FFN + scol;

    ushort* lA0 = As + wv * 512;
    ushort* lA1 = As + 2048 + wv * 512;
    ushort* lB0 = Bs + wv * 512;
    ushort* lB1 = Bs + 2048 + wv * 512;

    f4v acc[4][4];
#pragma unroll
    for (int i = 0; i < 4; ++i)
#pragma unroll
        for (int j = 0; j < 4; ++j) { f4v z = {0.f, 0.f, 0.f, 0.f}; acc[i][j] = z; }

    const int row_off = (wv & 1) * 64;
    const int col_off = (wv >> 1) * 64;
    const int l15 = lane & 15;
    const int lq  = lane >> 4;

    for (int k0 = 0; k0 < FFN; k0 += 32) {
        GLDS16(gA0 + k0, lA0);
        GLDS16(gA1 + k0, lA1);
        GLDS16(gB0 + k0, lB0);
        GLDS16(gB1 + k0, lB1);
        __syncthreads();
        s8v a[4], b[4];
#pragma unroll
        for (int i = 0; i < 4; ++i) a[i] = *(const s8v*)(As + (row_off + i * 16 + l15) * 32 + lq * 8);
#pragma unroll
        for (int j = 0; j < 4; ++j) b[j] = *(const s8v*)(Bs + (col_off + j * 16 + l15) * 32 + lq * 8);
#pragma unroll
        for (int i = 0; i < 4; ++i)
#pragma unroll
            for (int j = 0; j < 4; ++j)
                acc[i][j] = __builtin_amdgcn_mfma_f32_16x16x32_bf16(a[i], b[j], acc[i][j], 0, 0, 0);
        __syncthreads();
    }

    const int mrem = n_e - tile_m * 128;
#pragma unroll
    for (int i = 0; i < 4; ++i) {
#pragma unroll
        for (int r = 0; r < 4; ++r) {
            const int m_loc = row_off + i * 16 + lq * 4 + r;
            if (m_loc < mrem) {
                const int slot = base + tile_m * 128 + m_loc;
                const float wgt = weight_list[slot];
#pragma unroll
                for (int j = 0; j < 4; ++j) {
                    const int colD = tile_n * 128 + col_off + j * 16 + l15;
                    const float v = acc[i][j][r] + b2[e * HIDDEN + colD];
                    y[(size_t)slot * HIDDEN + colD] = f2bf(v * wgt);
                }
            }
        }
    }
}

// ---------------- combine: out[t] = y[slot0] + y[slot1]  (fp32 out) ----------------
__global__ void combine_kernel(const int* __restrict__ slot_of, const ushort* __restrict__ y,
                               float* __restrict__ out) {
    const int idx = blockIdx.x * blockDim.x + threadIdx.x;  // T * D/4 threads
    const int t = idx >> 8;             // D/4 = 256 vec4 per token
    const int d = (idx & 255) * 4;
    const int s0 = slot_of[t * 2 + 0];
    const int s1 = slot_of[t * 2 + 1];
    const ushort4 a = *(const ushort4*)(y + (size_t)s0 * HIDDEN + d);
    const ushort4 b = *(const ushort4*)(y + (size_t)s1 * HIDDEN + d);
    float4 o;
    o.x = bf2f(a.x) + bf2f(b.x);
    o.y = bf2f(a.y) + bf2f(b.y);
    o.z = bf2f(a.z) + bf2f(b.z);
    o.w = bf2f(a.w) + bf2f(b.w);
    *(float4*)(out + (size_t)t * HIDDEN + d) = o;
}

extern "C" void kernel_launch(void* const* d_in, const int* in_sizes, int n_in,
                              void* d_out, int out_size, void* d_ws, size_t ws_size,
                              hipStream_t stream) {
    const float* x  = (const float*)d_in[0];   // [T, D] fp32
    const float* Wr = (const float*)d_in[1];   // [E, D]
    const float* W1 = (const float*)d_in[2];   // [E, F, D]
    const float* b1 = (const float*)d_in[3];   // [E, F]
    const float* W2 = (const float*)d_in[4];   // [E, D, F]
    const float* b2 = (const float*)d_in[5];   // [E, D]
    float* out = (float*)d_out;

    char* ws = (char*)d_ws;
    int*    counts      = (int*)(ws + 0);
    int*    offsets     = (int*)(ws + 256);
    int*    cursors     = (int*)(ws + 512);
    int*    topk_idx    = (int*)(ws + 1024);
    float*  topk_w      = (float*)(ws + 1024 + 32768);
    int*    slot_of     = (int*)(ws + 1024 + 65536);
    int*    token_list  = (int*)(ws + 1024 + 98304);
    float*  weight_list = (float*)(ws + 1024 + 131072);
    ushort* x_bf        = (ushort*)(ws + (1 << 20));                             //  8 MB
    ushort* wbuf        = (ushort*)(ws + (1 << 20) + 8388608);                   // 64 MB (shared W1/W2)
    ushort* h           = (ushort*)(ws + (1 << 20) + 8388608 + 67108864);        // 64 MB
    ushort* y           = (ushort*)(ws + (1 << 20) + 8388608 + 2 * 67108864ull); // 16 MB

    const int NW = NEXP * FFN * HIDDEN;  // 33554432 elements per weight tensor

    hipMemsetAsync(counts, 0, 64, stream);
    // x -> bf16
    conv_kernel<<<(TOKENS * HIDDEN / 4) / 256, 256, 0, stream>>>((const float4*)x, (ushort4*)x_bf);
    // W1 -> bf16 (into shared wbuf)
    conv_kernel<<<(NW / 4) / 256, 256, 0, stream>>>((const float4*)W1, (ushort4*)wbuf);

    router_kernel<<<TOKENS, 64, 0, stream>>>(x, Wr, counts, topk_idx, topk_w);
    prefix_kernel<<<1, 64, 0, stream>>>(counts, offsets, cursors);
    scatter_kernel<<<ASSIGN / 256, 256, 0, stream>>>(topk_idx, topk_w, cursors,
                                                     token_list, weight_list, slot_of);

    gemm1_kernel<<<dim3(FFN / 128, ASSIGN / 128, NEXP), 256, 0, stream>>>(
        x_bf, wbuf, b1, token_list, counts, offsets, h);

    // W2 -> bf16 (reuse wbuf; stream-serial so gemm1 has finished reading W1)
    conv_kernel<<<(NW / 4) / 256, 256, 0, stream>>>((const float4*)W2, (ushort4*)wbuf);

    gemm2_kernel<<<dim3(HIDDEN / 128, ASSIGN / 128, NEXP), 256, 0, stream>>>(
        h, wbuf, b2, weight_list, counts, offsets, y);

    combine_kernel<<<(TOKENS * HIDDEN / 4) / 256, 256, 0, stream>>>(slot_of, y, out);
}